// Round 6
// baseline (404.939 us; speedup 1.0000x reference)
//
#include <hip/hip_runtime.h>
#include <hip/hip_bf16.h>

#define NN 100000
#define NE 1600000
#define DIN 512
#define DH 128
#define DOUT 64

#define BSH 9                    // bucket = dst >> 9  (512 nodes per bucket)
#define NB ((NN + 511) / 512)    // 196 buckets
#define P1B 512                  // edge-partition blocks for count/write phases
#define EPB ((NE + P1B - 1) / P1B)  // 3125 edges per partition

typedef __bf16 bf16_t;
typedef __bf16 bf16x8 __attribute__((ext_vector_type(8)));
typedef float f32x4 __attribute__((ext_vector_type(4)));

__device__ __forceinline__ float bflo(unsigned v) { return __int_as_float(v << 16); }
__device__ __forceinline__ float bfhi(unsigned v) { return __int_as_float(v & 0xffff0000u); }
__device__ __forceinline__ unsigned packbf2(float a, float b) {
    unsigned short ua = __builtin_bit_cast(unsigned short, (bf16_t)a);
    unsigned short ub = __builtin_bit_cast(unsigned short, (bf16_t)b);
    return (unsigned)ua | ((unsigned)ub << 16);
}

// ---------------- x -> bf16, streaming at HBM rate ----------------
__global__ __launch_bounds__(256) void xconvert_kernel(const float* __restrict__ x,
                                                       bf16_t* __restrict__ xb) {
    const long long total = (long long)NN * DIN;   // 51.2M, divisible by 8
    long long i = ((long long)blockIdx.x * 256 + threadIdx.x) * 8;
    const long long stride = (long long)gridDim.x * 256 * 8;
    for (; i < total; i += stride) {
        float4 a = *(const float4*)&x[i];
        float4 b = *(const float4*)&x[i + 4];
        uint4 o = make_uint4(packbf2(a.x, a.y), packbf2(a.z, a.w),
                             packbf2(b.x, b.y), packbf2(b.z, b.w));
        *(uint4*)&xb[i] = o;
    }
}

// ---------------- weight conversion: w1,w2 -> bf16 ----------------
__global__ __launch_bounds__(256) void convert_w_kernel(const float* __restrict__ w1,
                                                        const float* __restrict__ w2,
                                                        bf16_t* __restrict__ w1b,
                                                        bf16_t* __restrict__ w2b) {
    int i = blockIdx.x * 256 + threadIdx.x;
    if (i < DH * DIN) w1b[i] = (bf16_t)w1[i];
    if (i < DOUT * DH) w2b[i] = (bf16_t)w2[i];
}

// ---------------- GEMM1: h1b[N,128] = xb @ w1b^T, MFMA, BM=64, dense bf16 A-loads ----------------
__global__ __launch_bounds__(256) void gemm1_mfma(const bf16_t* __restrict__ xb,
                                                  const bf16_t* __restrict__ w1b,
                                                  bf16_t* __restrict__ h1b) {
    const int t = threadIdx.x;
    const int wv = t >> 6, lane = t & 63;
    const int fr = lane & 15, fq = lane >> 4;
    const int rbase = blockIdx.x * 64 + wv * 16;

    f32x4 acc[8];
#pragma unroll
    for (int n = 0; n < 8; n++) acc[n] = (f32x4)0.f;

    int r = rbase + fr;
    int rc = r < NN ? r : NN - 1;
    const bf16_t* pa = xb + (size_t)rc * DIN + fq * 8;
    const bf16_t* pb = w1b + (size_t)fr * DIN + fq * 8;

#pragma unroll 4
    for (int kk = 0; kk < DIN / 32; kk++) {
        bf16x8 af = *(const bf16x8*)(pa + kk * 32);
        bf16x8 bfr[8];
#pragma unroll
        for (int n = 0; n < 8; n++)
            bfr[n] = *(const bf16x8*)(pb + (size_t)n * 16 * DIN + kk * 32);
#pragma unroll
        for (int n = 0; n < 8; n++)
            acc[n] = __builtin_amdgcn_mfma_f32_16x16x32_bf16(af, bfr[n], acc[n], 0, 0, 0);
    }
#pragma unroll
    for (int j = 0; j < 4; j++) {
        int row = rbase + fq * 4 + j;
        if (row < NN) {
#pragma unroll
            for (int n = 0; n < 8; n++)
                h1b[(size_t)row * DH + n * 16 + fr] = (bf16_t)acc[n][j];
        }
    }
}

// ================= CSR build: two-level counting sort =================
__global__ __launch_bounds__(256) void p1_count(const int* __restrict__ edst,
                                                int* __restrict__ counts) {  // [P1B][256]
    __shared__ int h[NB];
    int blk = blockIdx.x, t = threadIdx.x;
    for (int i = t; i < NB; i += 256) h[i] = 0;
    __syncthreads();
    int e0 = blk * EPB, e1 = min(e0 + EPB, NE);
    for (int e = e0 + t; e < e1; e += 256) atomicAdd(&h[edst[e] >> BSH], 1);
    __syncthreads();
    for (int i = t; i < NB; i += 256) counts[blk * 256 + i] = h[i];
}

__global__ __launch_bounds__(256) void p2_scanblocks(const int* __restrict__ counts,
                                                     int* __restrict__ blockoffs,  // [P1B][256]
                                                     int* __restrict__ btotal) {   // [NB]
    __shared__ int s[512];
    int b = blockIdx.x, t = threadIdx.x;
    int c0 = counts[t * 256 + b];
    int c1 = counts[(t + 256) * 256 + b];
    s[t] = c0; s[t + 256] = c1;
    __syncthreads();
    for (int off = 1; off < 512; off <<= 1) {
        int v0 = (t >= off) ? s[t - off] : 0;
        int v1 = (t + 256 >= off) ? s[t + 256 - off] : 0;
        __syncthreads();
        s[t] += v0; s[t + 256] += v1;
        __syncthreads();
    }
    blockoffs[t * 256 + b] = s[t] - c0;
    blockoffs[(t + 256) * 256 + b] = s[t + 256] - c1;
    if (t == 0) btotal[b] = s[511];
}

__global__ __launch_bounds__(256) void p3_scanbuckets(const int* __restrict__ btotal,
                                                      int* __restrict__ bbase,
                                                      int* __restrict__ rowptr) {
    __shared__ int s[256];
    int t = threadIdx.x;
    int self = (t < NB) ? btotal[t] : 0;
    s[t] = self;
    __syncthreads();
    for (int off = 1; off < 256; off <<= 1) {
        int v = (t >= off) ? s[t - off] : 0;
        __syncthreads();
        s[t] += v;
        __syncthreads();
    }
    if (t < NB) bbase[t] = s[t] - self;
    if (t == 0) rowptr[NN] = NE;
}

__global__ __launch_bounds__(256) void p4_bucketwrite(const int* __restrict__ esrc,
                                                      const int* __restrict__ edst,
                                                      const float* __restrict__ ew,
                                                      const int* __restrict__ blockoffs,
                                                      const int* __restrict__ bbase,
                                                      int2* __restrict__ bsrcw,
                                                      unsigned short* __restrict__ bdst16) {
    __shared__ int cur[NB];
    int blk = blockIdx.x, t = threadIdx.x;
    for (int i = t; i < NB; i += 256) cur[i] = bbase[i] + blockoffs[blk * 256 + i];
    __syncthreads();
    int e0 = blk * EPB, e1 = min(e0 + EPB, NE);
    for (int e = e0 + t; e < e1; e += 256) {
        int d = edst[e];
        int b = d >> BSH;
        int pos = atomicAdd(&cur[b], 1);
        bsrcw[pos] = make_int2(esrc[e], __float_as_int(ew[e]));
        bdst16[pos] = (unsigned short)(d & 511);
    }
}

__global__ __launch_bounds__(256) void p5_bucketsort(const int2* __restrict__ bsrcw,
                                                     const unsigned short* __restrict__ bdst16,
                                                     const int* __restrict__ bbase,
                                                     const int* __restrict__ btotal,
                                                     int2* __restrict__ csr,
                                                     int* __restrict__ rowptr) {
    __shared__ int cnt[512];
    __shared__ int curs[512];
    __shared__ int sc[256];
    int b = blockIdx.x, t = threadIdx.x;
    int base = bbase[b], n = btotal[b];
    int node0 = b << BSH;
    cnt[t] = 0; cnt[t + 256] = 0;
    __syncthreads();
    for (int i = t; i < n; i += 256) atomicAdd(&cnt[bdst16[base + i]], 1);
    __syncthreads();
    int c0 = cnt[2 * t], c1 = cnt[2 * t + 1];
    sc[t] = c0 + c1;
    __syncthreads();
    for (int off = 1; off < 256; off <<= 1) {
        int v = (t >= off) ? sc[t - off] : 0;
        __syncthreads();
        sc[t] += v;
        __syncthreads();
    }
    int e0 = (t > 0) ? sc[t - 1] : 0;
    curs[2 * t] = e0;
    curs[2 * t + 1] = e0 + c0;
    int n0 = node0 + 2 * t, n1 = node0 + 2 * t + 1;
    if (n0 < NN) rowptr[n0] = base + e0;
    if (n1 < NN) rowptr[n1] = base + e0 + c0;
    __syncthreads();
    for (int i = t; i < n; i += 256) {
        unsigned short d = bdst16[base + i];
        int2 sw = bsrcw[base + i];
        int p = atomicAdd(&curs[d], 1);
        csr[base + p] = sw;
    }
}

// ---------------- fused: spmm128 gather (4-deep ILP) + relu + MFMA matvec -> h2b ----------------
__global__ __launch_bounds__(256) void spmm1_fused(const int2* __restrict__ csr,
                                                   const int* __restrict__ rowptr,
                                                   const bf16_t* __restrict__ h1b,
                                                   const bf16_t* __restrict__ w2b,
                                                   bf16_t* __restrict__ h2b) {
    __shared__ unsigned aggs[16][68];   // [node][k-pair], stride 68 dwords
    const int t = threadIdx.x;
    const int wv = t >> 6, lane = t & 63;
    const int nb = blockIdx.x * 16;     // NN % 16 == 0

#pragma unroll
    for (int q = 0; q < 4; q++) {
        int n = nb + wv * 4 + q;
        int st = rowptr[n], end = rowptr[n + 1];
        float ax = 0.f, ay = 0.f;
        for (int i = st; i < end; i += 4) {
            bool b1 = (i + 1 < end), b2 = (i + 2 < end), b3 = (i + 3 < end);
            int2 e0 = csr[i];
            int2 e1 = csr[b1 ? i + 1 : st];
            int2 e2 = csr[b2 ? i + 2 : st];
            int2 e3 = csr[b3 ? i + 3 : st];
            float w0 = __int_as_float(e0.y);
            float w1 = b1 ? __int_as_float(e1.y) : 0.f;
            float w2 = b2 ? __int_as_float(e2.y) : 0.f;
            float w3 = b3 ? __int_as_float(e3.y) : 0.f;
            unsigned v0 = *(const unsigned*)&h1b[(size_t)e0.x * DH + lane * 2];
            unsigned v1 = *(const unsigned*)&h1b[(size_t)e1.x * DH + lane * 2];
            unsigned v2 = *(const unsigned*)&h1b[(size_t)e2.x * DH + lane * 2];
            unsigned v3 = *(const unsigned*)&h1b[(size_t)e3.x * DH + lane * 2];
            ax = fmaf(w0, bflo(v0), ax); ay = fmaf(w0, bfhi(v0), ay);
            ax = fmaf(w1, bflo(v1), ax); ay = fmaf(w1, bfhi(v1), ay);
            ax = fmaf(w2, bflo(v2), ax); ay = fmaf(w2, bfhi(v2), ay);
            ax = fmaf(w3, bflo(v3), ax); ay = fmaf(w3, bfhi(v3), ay);
        }
        ax = fmaxf(ax, 0.f); ay = fmaxf(ay, 0.f);     // relu
        aggs[wv * 4 + q][lane] = packbf2(ax, ay);
    }
    __syncthreads();

    // MFMA: A = aggs[16][128] (LDS), B = w2 rows wv*16..wv*16+15 (L2)
    const int fr = lane & 15, fq = lane >> 4;
    f32x4 acc = (f32x4)0.f;
    const bf16_t* pb = w2b + (size_t)(wv * 16 + fr) * DH + fq * 8;
    const bf16_t* arow = (const bf16_t*)aggs[fr];
#pragma unroll
    for (int kk = 0; kk < 4; kk++) {
        bf16x8 af = *(const bf16x8*)&arow[kk * 32 + fq * 8];
        bf16x8 bf = *(const bf16x8*)(pb + kk * 32);
        acc = __builtin_amdgcn_mfma_f32_16x16x32_bf16(af, bf, acc, 0, 0, 0);
    }
#pragma unroll
    for (int j = 0; j < 4; j++) {
        int node = nb + fq * 4 + j;
        h2b[(size_t)node * DOUT + wv * 16 + fr] = (bf16_t)acc[j];
    }
}

// ---------------- SpMM-CSR d=64 + fused log_softmax (4 edges in flight) ----------------
__global__ __launch_bounds__(256) void spmm64_ls_kernel(const int2* __restrict__ csr,
                                                        const int* __restrict__ rowptr,
                                                        const bf16_t* __restrict__ h2b,
                                                        float* __restrict__ outp) {
    int n = blockIdx.x * 4 + (threadIdx.x >> 6);
    int lane = threadIdx.x & 63;
    int half = lane >> 5, lc = lane & 31;
    if (n >= NN) return;
    int st = rowptr[n], end = rowptr[n + 1];
    float ax = 0.f, ay = 0.f;
    for (int i = st; i < end; i += 4) {
        int ia = i + half * 2;
        bool b0 = (ia < end), b1 = (ia + 1 < end);
        int2 e0 = csr[b0 ? ia : st];
        int2 e1 = csr[b1 ? ia + 1 : st];
        float w0 = b0 ? __int_as_float(e0.y) : 0.f;
        float w1 = b1 ? __int_as_float(e1.y) : 0.f;
        unsigned v0 = *(const unsigned*)&h2b[(size_t)e0.x * DOUT + lc * 2];
        unsigned v1 = *(const unsigned*)&h2b[(size_t)e1.x * DOUT + lc * 2];
        ax = fmaf(w0, bflo(v0), ax); ay = fmaf(w0, bfhi(v0), ay);
        ax = fmaf(w1, bflo(v1), ax); ay = fmaf(w1, bfhi(v1), ay);
    }
    ax += __shfl_xor(ax, 32);
    ay += __shfl_xor(ay, 32);
    float m = fmaxf(ax, ay);
#pragma unroll
    for (int off = 16; off >= 1; off >>= 1) m = fmaxf(m, __shfl_xor(m, off));
    float s = expf(ax - m) + expf(ay - m);
#pragma unroll
    for (int off = 16; off >= 1; off >>= 1) s += __shfl_xor(s, off);
    float ls = logf(s);
    if (half == 0) {
        float2 o = make_float2(ax - m - ls, ay - m - ls);
        *(float2*)&outp[(size_t)n * DOUT + lc * 2] = o;
    }
}

extern "C" void kernel_launch(void* const* d_in, const int* in_sizes, int n_in,
                              void* d_out, int out_size, void* d_ws, size_t ws_size,
                              hipStream_t stream) {
    const float* x  = (const float*)d_in[0];
    const float* w1 = (const float*)d_in[1];
    const float* w2 = (const float*)d_in[2];
    const int* esrc = (const int*)d_in[3];
    const int* edst = (const int*)d_in[4];
    const float* ew = (const float*)d_in[5];
    float* out = (float*)d_out;

    char* ws = (char*)d_ws;
    size_t off = 0;
    auto alloc = [&](size_t bytes) {
        void* p = ws + off;
        off = (off + bytes + 255) & ~(size_t)255;
        return p;
    };
    bf16_t* xb       = (bf16_t*)alloc((size_t)NN * DIN * 2);     // 102.4 MB
    bf16_t* h1b      = (bf16_t*)alloc((size_t)NN * DH * 2);      // 25.6 MB
    bf16_t* h2b      = (bf16_t*)alloc((size_t)NN * DOUT * 2);    // 12.8 MB
    bf16_t* w1b      = (bf16_t*)alloc((size_t)DH * DIN * 2);
    bf16_t* w2b      = (bf16_t*)alloc((size_t)DOUT * DH * 2);
    int2*   csr      = (int2*)alloc((size_t)(NE + 8) * 8);       // 12.8 MB
    int2*   bsrcw    = (int2*)alloc((size_t)NE * 8);             // 12.8 MB
    unsigned short* bdst16 = (unsigned short*)alloc((size_t)NE * 2);
    int*    rowptr   = (int*)alloc((size_t)(NN + 1) * 4);
    int*    counts   = (int*)alloc((size_t)P1B * 256 * 4);
    int*    blockoffs= (int*)alloc((size_t)P1B * 256 * 4);
    int*    btotal   = (int*)alloc((size_t)256 * 4);
    int*    bbase    = (int*)alloc((size_t)256 * 4);

    // 0. conversions
    convert_w_kernel<<<(DH * DIN + 255) / 256, 256, 0, stream>>>(w1, w2, w1b, w2b);
    xconvert_kernel<<<2048, 256, 0, stream>>>(x, xb);
    // 1. h1b = xb @ w1b^T
    gemm1_mfma<<<(NN + 63) / 64, 256, 0, stream>>>(xb, w1b, h1b);
    // 2. CSR build
    p1_count<<<P1B, 256, 0, stream>>>(edst, counts);
    p2_scanblocks<<<NB, 256, 0, stream>>>(counts, blockoffs, btotal);
    p3_scanbuckets<<<1, 256, 0, stream>>>(btotal, bbase, rowptr);
    p4_bucketwrite<<<P1B, 256, 0, stream>>>(esrc, edst, ew, blockoffs, bbase, bsrcw, bdst16);
    p5_bucketsort<<<NB, 256, 0, stream>>>(bsrcw, bdst16, bbase, btotal, csr, rowptr);
    // 3+4. h2b = relu(SpMM(h1b)) @ w2^T   (fused, MFMA epilogue)
    spmm1_fused<<<NN / 16, 256, 0, stream>>>(csr, rowptr, h1b, w2b, h2b);
    // 5. out = log_softmax(SpMM(h2b))
    spmm64_ls_kernel<<<(NN + 3) / 4, 256, 0, stream>>>(csr, rowptr, h2b, out);
}

// Round 7
// 293.460 us; speedup vs baseline: 1.3799x; 1.3799x over previous
//
#include <hip/hip_runtime.h>
#include <hip/hip_bf16.h>

#define NN 100000
#define NE 1600000
#define DIN 512
#define DH 128
#define DOUT 64

#define BSH 9                    // bucket = dst >> 9  (512 nodes per bucket)
#define NB ((NN + 511) / 512)    // 196 buckets
#define P1B 512                  // edge-partition blocks for count/write phases
#define EPB ((NE + P1B - 1) / P1B)  // 3125 edges per partition

typedef __bf16 bf16_t;
typedef __bf16 bf16x8 __attribute__((ext_vector_type(8)));
typedef float f32x4 __attribute__((ext_vector_type(4)));

__device__ __forceinline__ float bflo(unsigned v) { return __int_as_float(v << 16); }
__device__ __forceinline__ float bfhi(unsigned v) { return __int_as_float(v & 0xffff0000u); }
__device__ __forceinline__ unsigned packbf2(float a, float b) {
    unsigned short ua = __builtin_bit_cast(unsigned short, (bf16_t)a);
    unsigned short ub = __builtin_bit_cast(unsigned short, (bf16_t)b);
    return (unsigned)ua | ((unsigned)ub << 16);
}

// ---------------- weight conversion: w1,w2 -> bf16 ----------------
__global__ __launch_bounds__(256) void convert_w_kernel(const float* __restrict__ w1,
                                                        const float* __restrict__ w2,
                                                        bf16_t* __restrict__ w1b,
                                                        bf16_t* __restrict__ w2b) {
    int i = blockIdx.x * 256 + threadIdx.x;
    if (i < DH * DIN) w1b[i] = (bf16_t)w1[i];
    if (i < DOUT * DH) w2b[i] = (bf16_t)w2[i];
}

// ---------------- GEMM1: h1b[N,128] = bf16(x) @ w1b^T ----------------
// m97-style LDS-staged MFMA. BM=128, BN=128(all), BK=64, 4 waves.
// A: reg-staged fp32->bf16, ds_write_b128, XOR-swizzled (slot ^= row&7).
// B: global_load_lds width=16 (linear LDS dest) + inverse-swizzled GLOBAL source.
// Reads: ds_read_b128 at slot (kk*4+fq)^(row&7)  -> conflict-free.
__global__ __launch_bounds__(256) void gemm1_mfma(const float* __restrict__ x,
                                                  const bf16_t* __restrict__ w1b,
                                                  bf16_t* __restrict__ h1b) {
    __shared__ __align__(16) char AsB[128 * 128];   // 128 rows x 128 B (64 bf16)
    __shared__ __align__(16) char BsB[128 * 128];
    const int t = threadIdx.x;
    const int wv = t >> 6, lane = t & 63;
    const int fr = lane & 15, fq = lane >> 4;
    const int rbase = blockIdx.x * 128;

    f32x4 acc[2][8];
#pragma unroll
    for (int m = 0; m < 2; m++)
#pragma unroll
        for (int n = 0; n < 8; n++) acc[m][n] = (f32x4)0.f;

    for (int k0 = 0; k0 < DIN; k0 += 64) {
        // ---- stage A (128x64 fp32 -> bf16, swizzled ds_write) ----
#pragma unroll
        for (int j = 0; j < 4; j++) {
            int c = j * 256 + t;            // 1024 chunks of 8 elements
            int row = c >> 3, k8 = c & 7;
            int gr = rbase + row;
            int grc = gr < NN ? gr : NN - 1;
            const float* src = x + (size_t)grc * DIN + k0 + k8 * 8;
            float4 a = *(const float4*)src;
            float4 b = *(const float4*)(src + 4);
            bf16x8 v;
            v[0] = (bf16_t)a.x; v[1] = (bf16_t)a.y; v[2] = (bf16_t)a.z; v[3] = (bf16_t)a.w;
            v[4] = (bf16_t)b.x; v[5] = (bf16_t)b.y; v[6] = (bf16_t)b.z; v[7] = (bf16_t)b.w;
            *(bf16x8*)&AsB[row * 128 + ((k8 ^ (row & 7)) * 16)] = v;
        }
        // ---- stage B (128x64 bf16) via global_load_lds, pre-swizzled source ----
#pragma unroll
        for (int i = 0; i < 4; i++) {
            int c = i * 256 + wv * 64 + lane;   // chunk index = phys LDS byte / 16
            int cr = c >> 3, sp = c & 7;
            const bf16_t* gsrc = w1b + (size_t)cr * DIN + k0 + ((sp ^ (cr & 7)) * 8);
            __builtin_amdgcn_global_load_lds(
                (const __attribute__((address_space(1))) void*)gsrc,
                (__attribute__((address_space(3))) void*)(BsB + i * 4096 + wv * 1024),
                16, 0, 0);
        }
        __syncthreads();

        // ---- compute: 2 kk x (2m A-frags, 8n B-frags, 16 MFMA) ----
#pragma unroll
        for (int kk = 0; kk < 2; kk++) {
            bf16x8 af[2];
#pragma unroll
            for (int m = 0; m < 2; m++) {
                int R = wv * 32 + m * 16 + fr;
                af[m] = *(const bf16x8*)&AsB[R * 128 + (((kk * 4 + fq) ^ (R & 7)) * 16)];
            }
#pragma unroll
            for (int n = 0; n < 8; n++) {
                int cr = n * 16 + fr;
                bf16x8 bf = *(const bf16x8*)&BsB[cr * 128 + (((kk * 4 + fq) ^ (cr & 7)) * 16)];
                acc[0][n] = __builtin_amdgcn_mfma_f32_16x16x32_bf16(af[0], bf, acc[0][n], 0, 0, 0);
                acc[1][n] = __builtin_amdgcn_mfma_f32_16x16x32_bf16(af[1], bf, acc[1][n], 0, 0, 0);
            }
        }
        __syncthreads();
    }
#pragma unroll
    for (int m = 0; m < 2; m++)
#pragma unroll
        for (int j = 0; j < 4; j++) {
            int row = rbase + wv * 32 + m * 16 + fq * 4 + j;
            if (row < NN) {
#pragma unroll
                for (int n = 0; n < 8; n++)
                    h1b[(size_t)row * DH + n * 16 + fr] = (bf16_t)acc[m][n][j];
            }
        }
}

// ================= CSR build: two-level counting sort =================
__global__ __launch_bounds__(256) void p1_count(const int* __restrict__ edst,
                                                int* __restrict__ counts) {  // [P1B][256]
    __shared__ int h[NB];
    int blk = blockIdx.x, t = threadIdx.x;
    for (int i = t; i < NB; i += 256) h[i] = 0;
    __syncthreads();
    int e0 = blk * EPB, e1 = min(e0 + EPB, NE);
    for (int e = e0 + t; e < e1; e += 256) atomicAdd(&h[edst[e] >> BSH], 1);
    __syncthreads();
    for (int i = t; i < NB; i += 256) counts[blk * 256 + i] = h[i];
}

__global__ __launch_bounds__(256) void p2_scanblocks(const int* __restrict__ counts,
                                                     int* __restrict__ blockoffs,  // [P1B][256]
                                                     int* __restrict__ btotal) {   // [NB]
    __shared__ int s[512];
    int b = blockIdx.x, t = threadIdx.x;
    int c0 = counts[t * 256 + b];
    int c1 = counts[(t + 256) * 256 + b];
    s[t] = c0; s[t + 256] = c1;
    __syncthreads();
    for (int off = 1; off < 512; off <<= 1) {
        int v0 = (t >= off) ? s[t - off] : 0;
        int v1 = (t + 256 >= off) ? s[t + 256 - off] : 0;
        __syncthreads();
        s[t] += v0; s[t + 256] += v1;
        __syncthreads();
    }
    blockoffs[t * 256 + b] = s[t] - c0;
    blockoffs[(t + 256) * 256 + b] = s[t + 256] - c1;
    if (t == 0) btotal[b] = s[511];
}

__global__ __launch_bounds__(256) void p3_scanbuckets(const int* __restrict__ btotal,
                                                      int* __restrict__ bbase,
                                                      int* __restrict__ rowptr) {
    __shared__ int s[256];
    int t = threadIdx.x;
    int self = (t < NB) ? btotal[t] : 0;
    s[t] = self;
    __syncthreads();
    for (int off = 1; off < 256; off <<= 1) {
        int v = (t >= off) ? s[t - off] : 0;
        __syncthreads();
        s[t] += v;
        __syncthreads();
    }
    if (t < NB) bbase[t] = s[t] - self;
    if (t == 0) rowptr[NN] = NE;
}

__global__ __launch_bounds__(256) void p4_bucketwrite(const int* __restrict__ esrc,
                                                      const int* __restrict__ edst,
                                                      const float* __restrict__ ew,
                                                      const int* __restrict__ blockoffs,
                                                      const int* __restrict__ bbase,
                                                      int2* __restrict__ bsrcw,
                                                      unsigned short* __restrict__ bdst16) {
    __shared__ int cur[NB];
    int blk = blockIdx.x, t = threadIdx.x;
    for (int i = t; i < NB; i += 256) cur[i] = bbase[i] + blockoffs[blk * 256 + i];
    __syncthreads();
    int e0 = blk * EPB, e1 = min(e0 + EPB, NE);
    for (int e = e0 + t; e < e1; e += 256) {
        int d = edst[e];
        int b = d >> BSH;
        int pos = atomicAdd(&cur[b], 1);
        bsrcw[pos] = make_int2(esrc[e], __float_as_int(ew[e]));
        bdst16[pos] = (unsigned short)(d & 511);
    }
}

__global__ __launch_bounds__(256) void p5_bucketsort(const int2* __restrict__ bsrcw,
                                                     const unsigned short* __restrict__ bdst16,
                                                     const int* __restrict__ bbase,
                                                     const int* __restrict__ btotal,
                                                     int2* __restrict__ csr,
                                                     int* __restrict__ rowptr) {
    __shared__ int cnt[512];
    __shared__ int curs[512];
    __shared__ int sc[256];
    int b = blockIdx.x, t = threadIdx.x;
    int base = bbase[b], n = btotal[b];
    int node0 = b << BSH;
    cnt[t] = 0; cnt[t + 256] = 0;
    __syncthreads();
    for (int i = t; i < n; i += 256) atomicAdd(&cnt[bdst16[base + i]], 1);
    __syncthreads();
    int c0 = cnt[2 * t], c1 = cnt[2 * t + 1];
    sc[t] = c0 + c1;
    __syncthreads();
    for (int off = 1; off < 256; off <<= 1) {
        int v = (t >= off) ? sc[t - off] : 0;
        __syncthreads();
        sc[t] += v;
        __syncthreads();
    }
    int e0 = (t > 0) ? sc[t - 1] : 0;
    curs[2 * t] = e0;
    curs[2 * t + 1] = e0 + c0;
    int n0 = node0 + 2 * t, n1 = node0 + 2 * t + 1;
    if (n0 < NN) rowptr[n0] = base + e0;
    if (n1 < NN) rowptr[n1] = base + e0 + c0;
    __syncthreads();
    for (int i = t; i < n; i += 256) {
        unsigned short d = bdst16[base + i];
        int2 sw = bsrcw[base + i];
        int p = atomicAdd(&curs[d], 1);
        csr[base + p] = sw;
    }
}

// ---------------- fused: spmm128 gather (4-deep ILP) + relu + MFMA matvec -> h2b ----------------
__global__ __launch_bounds__(256) void spmm1_fused(const int2* __restrict__ csr,
                                                   const int* __restrict__ rowptr,
                                                   const bf16_t* __restrict__ h1b,
                                                   const bf16_t* __restrict__ w2b,
                                                   bf16_t* __restrict__ h2b) {
    __shared__ unsigned aggs[16][68];   // [node][k-pair], stride 68 dwords
    const int t = threadIdx.x;
    const int wv = t >> 6, lane = t & 63;
    const int nb = blockIdx.x * 16;     // NN % 16 == 0

#pragma unroll
    for (int q = 0; q < 4; q++) {
        int n = nb + wv * 4 + q;
        int st = rowptr[n], end = rowptr[n + 1];
        float ax = 0.f, ay = 0.f;
        for (int i = st; i < end; i += 4) {
            bool b1 = (i + 1 < end), b2 = (i + 2 < end), b3 = (i + 3 < end);
            int2 e0 = csr[i];
            int2 e1 = csr[b1 ? i + 1 : st];
            int2 e2 = csr[b2 ? i + 2 : st];
            int2 e3 = csr[b3 ? i + 3 : st];
            float w0 = __int_as_float(e0.y);
            float w1 = b1 ? __int_as_float(e1.y) : 0.f;
            float w2 = b2 ? __int_as_float(e2.y) : 0.f;
            float w3 = b3 ? __int_as_float(e3.y) : 0.f;
            unsigned v0 = *(const unsigned*)&h1b[(size_t)e0.x * DH + lane * 2];
            unsigned v1 = *(const unsigned*)&h1b[(size_t)e1.x * DH + lane * 2];
            unsigned v2 = *(const unsigned*)&h1b[(size_t)e2.x * DH + lane * 2];
            unsigned v3 = *(const unsigned*)&h1b[(size_t)e3.x * DH + lane * 2];
            ax = fmaf(w0, bflo(v0), ax); ay = fmaf(w0, bfhi(v0), ay);
            ax = fmaf(w1, bflo(v1), ax); ay = fmaf(w1, bfhi(v1), ay);
            ax = fmaf(w2, bflo(v2), ax); ay = fmaf(w2, bfhi(v2), ay);
            ax = fmaf(w3, bflo(v3), ax); ay = fmaf(w3, bfhi(v3), ay);
        }
        ax = fmaxf(ax, 0.f); ay = fmaxf(ay, 0.f);     // relu
        aggs[wv * 4 + q][lane] = packbf2(ax, ay);
    }
    __syncthreads();

    // MFMA: A = aggs[16][128] (LDS), B = w2 rows wv*16..wv*16+15 (L2)
    const int fr = lane & 15, fq = lane >> 4;
    f32x4 acc = (f32x4)0.f;
    const bf16_t* pb = w2b + (size_t)(wv * 16 + fr) * DH + fq * 8;
    const bf16_t* arow = (const bf16_t*)aggs[fr];
#pragma unroll
    for (int kk = 0; kk < 4; kk++) {
        bf16x8 af = *(const bf16x8*)&arow[kk * 32 + fq * 8];
        bf16x8 bf = *(const bf16x8*)(pb + kk * 32);
        acc = __builtin_amdgcn_mfma_f32_16x16x32_bf16(af, bf, acc, 0, 0, 0);
    }
#pragma unroll
    for (int j = 0; j < 4; j++) {
        int node = nb + fq * 4 + j;
        h2b[(size_t)node * DOUT + wv * 16 + fr] = (bf16_t)acc[j];
    }
}

// ---------------- SpMM-CSR d=64 + fused log_softmax (4 edges in flight) ----------------
__global__ __launch_bounds__(256) void spmm64_ls_kernel(const int2* __restrict__ csr,
                                                        const int* __restrict__ rowptr,
                                                        const bf16_t* __restrict__ h2b,
                                                        float* __restrict__ outp) {
    int n = blockIdx.x * 4 + (threadIdx.x >> 6);
    int lane = threadIdx.x & 63;
    int half = lane >> 5, lc = lane & 31;
    if (n >= NN) return;
    int st = rowptr[n], end = rowptr[n + 1];
    float ax = 0.f, ay = 0.f;
    for (int i = st; i < end; i += 4) {
        int ia = i + half * 2;
        bool b0 = (ia < end), b1 = (ia + 1 < end);
        int2 e0 = csr[b0 ? ia : st];
        int2 e1 = csr[b1 ? ia + 1 : st];
        float w0 = b0 ? __int_as_float(e0.y) : 0.f;
        float w1 = b1 ? __int_as_float(e1.y) : 0.f;
        unsigned v0 = *(const unsigned*)&h2b[(size_t)e0.x * DOUT + lc * 2];
        unsigned v1 = *(const unsigned*)&h2b[(size_t)e1.x * DOUT + lc * 2];
        ax = fmaf(w0, bflo(v0), ax); ay = fmaf(w0, bfhi(v0), ay);
        ax = fmaf(w1, bflo(v1), ax); ay = fmaf(w1, bfhi(v1), ay);
    }
    ax += __shfl_xor(ax, 32);
    ay += __shfl_xor(ay, 32);
    float m = fmaxf(ax, ay);
#pragma unroll
    for (int off = 16; off >= 1; off >>= 1) m = fmaxf(m, __shfl_xor(m, off));
    float s = expf(ax - m) + expf(ay - m);
#pragma unroll
    for (int off = 16; off >= 1; off >>= 1) s += __shfl_xor(s, off);
    float ls = logf(s);
    if (half == 0) {
        float2 o = make_float2(ax - m - ls, ay - m - ls);
        *(float2*)&outp[(size_t)n * DOUT + lc * 2] = o;
    }
}

extern "C" void kernel_launch(void* const* d_in, const int* in_sizes, int n_in,
                              void* d_out, int out_size, void* d_ws, size_t ws_size,
                              hipStream_t stream) {
    const float* x  = (const float*)d_in[0];
    const float* w1 = (const float*)d_in[1];
    const float* w2 = (const float*)d_in[2];
    const int* esrc = (const int*)d_in[3];
    const int* edst = (const int*)d_in[4];
    const float* ew = (const float*)d_in[5];
    float* out = (float*)d_out;

    char* ws = (char*)d_ws;
    size_t off = 0;
    auto alloc = [&](size_t bytes) {
        void* p = ws + off;
        off = (off + bytes + 255) & ~(size_t)255;
        return p;
    };
    bf16_t* h1b      = (bf16_t*)alloc((size_t)NN * DH * 2);      // 25.6 MB
    bf16_t* h2b      = (bf16_t*)alloc((size_t)NN * DOUT * 2);    // 12.8 MB
    bf16_t* w1b      = (bf16_t*)alloc((size_t)DH * DIN * 2);
    bf16_t* w2b      = (bf16_t*)alloc((size_t)DOUT * DH * 2);
    int2*   csr      = (int2*)alloc((size_t)(NE + 8) * 8);       // 12.8 MB
    int2*   bsrcw    = (int2*)alloc((size_t)NE * 8);             // 12.8 MB
    unsigned short* bdst16 = (unsigned short*)alloc((size_t)NE * 2);
    int*    rowptr   = (int*)alloc((size_t)(NN + 1) * 4);
    int*    counts   = (int*)alloc((size_t)P1B * 256 * 4);
    int*    blockoffs= (int*)alloc((size_t)P1B * 256 * 4);
    int*    btotal   = (int*)alloc((size_t)256 * 4);
    int*    bbase    = (int*)alloc((size_t)256 * 4);

    // 0. weights -> bf16
    convert_w_kernel<<<(DH * DIN + 255) / 256, 256, 0, stream>>>(w1, w2, w1b, w2b);
    // 1. h1b = bf16(x) @ w1b^T   (LDS-staged MFMA)
    gemm1_mfma<<<(NN + 127) / 128, 256, 0, stream>>>(x, w1b, h1b);
    // 2. CSR build
    p1_count<<<P1B, 256, 0, stream>>>(edst, counts);
    p2_scanblocks<<<NB, 256, 0, stream>>>(counts, blockoffs, btotal);
    p3_scanbuckets<<<1, 256, 0, stream>>>(btotal, bbase, rowptr);
    p4_bucketwrite<<<P1B, 256, 0, stream>>>(esrc, edst, ew, blockoffs, bbase, bsrcw, bdst16);
    p5_bucketsort<<<NB, 256, 0, stream>>>(bsrcw, bdst16, bbase, btotal, csr, rowptr);
    // 3+4. h2b = relu(SpMM(h1b)) @ w2^T   (fused, MFMA epilogue)
    spmm1_fused<<<NN / 16, 256, 0, stream>>>(csr, rowptr, h1b, w2b, h2b);
    // 5. out = log_softmax(SpMM(h2b))
    spmm64_ls_kernel<<<(NN + 3) / 4, 256, 0, stream>>>(csr, rowptr, h2b, out);
}